// Round 2
// 2012.608 us; speedup vs baseline: 1.7857x; 1.7857x over previous
//
#include <hip/hip_runtime.h>
#include <cstdint>
#include <cstddef>

// RWKV-7 Tmix forward, MI355X gfx950 — ROUND 6: SPLIT-bf16 MFMA (fp32-accurate).
// Round-5 lesson: single bf16 GEMM error (~4e-3) is amplified up to 39x by
// GroupNorm (EPS=6.4e-4) -> absmax 0.465. Fix: compensated bf16 — each operand
// split hi/lo (hi=bf16(x), lo=bf16(x-hi)); acc = hi*hi + lo*hi + hi*lo gives
// per-term rel err ~2^-18 (fp32-class), still on the MFMA pipe (3x issue).
// B=2 T=1024 C=2048 H=32 N=64. Workspace high-water: 100608 KiB (unchanged).

#define DI __device__ __forceinline__
static constexpr int T_ = 1024, C_ = 2048, H_ = 32;

typedef __attribute__((ext_vector_type(8))) __bf16 bf16x8;
typedef __attribute__((ext_vector_type(4))) float f32x4;
typedef __attribute__((ext_vector_type(8))) unsigned short us8v;
typedef __attribute__((ext_vector_type(4))) unsigned short us4v;
typedef __attribute__((ext_vector_type(2))) unsigned short us2v;

DI float sig_(float z) { return 1.0f / (1.0f + expf(-z)); }

DI unsigned short f2bf(float f) {           // round-to-nearest-even f32 -> bf16
  union { float f; uint32_t u; } v; v.f = f;
  uint32_t u = v.u;
  return (unsigned short)((u + 0x7FFFu + ((u >> 16) & 1u)) >> 16);
}
DI float bf2f(unsigned short h) {
  union { uint32_t u; float f; } v; v.u = ((uint32_t)h) << 16;
  return v.f;
}

// ---------------- fp32 oracle GEMM (kept for G2: K<=128 LoRA-up jobs) ----------------
struct Job {
  const float* A; const float* W; float* C; const float* bias;
  const float* mixv; const float* x; const float* shift;
  int N, K, ntn, aact, epi, tile_end;
};
struct Jobs { Job j[7]; };

__global__ __launch_bounds__(256) void gemm_oracle(Jobs P) {
  __shared__ float As[64][33];
  __shared__ float Ws[32][65];
  int bx = blockIdx.x, ji = 0;
  while (bx >= P.j[ji].tile_end) ++ji;
  Job J = P.j[ji];
  int tix = bx - (ji ? P.j[ji - 1].tile_end : 0);
  int mt = tix / J.ntn, nt = tix % J.ntn;
  int m0 = mt * 64, n0 = nt * 64;
  int tid = threadIdx.x, tx = tid & 15, ty = tid >> 4;
  float acc[4][4] = {};
  for (int k0 = 0; k0 < J.K; k0 += 32) {
    #pragma unroll
    for (int p = 0; p < 8; ++p) {
      int idx = p * 256 + tid;
      int r = idx >> 5, kc = idx & 31;
      int m = m0 + r, k = k0 + kc;
      float a;
      if (J.mixv) {
        float xv = J.x[(size_t)m * C_ + k];
        int t = m & (T_ - 1);
        float xp = (t == 0) ? J.shift[(size_t)(m >> 10) * C_ + k]
                            : J.x[(size_t)(m - 1) * C_ + k];
        a = xv + (xp - xv) * J.mixv[k];
      } else {
        a = J.A[(size_t)m * J.K + k];
        if (J.aact == 1) a = tanhf(a);
        else if (J.aact == 2) a = sig_(a);
      }
      As[r][kc] = a;
    }
    #pragma unroll
    for (int p = 0; p < 8; ++p) {
      int idx = p * 256 + tid;
      int kr = idx >> 6, nc = idx & 63;
      int n = n0 + nc;
      Ws[kr][nc] = (n < J.N) ? J.W[(size_t)(k0 + kr) * J.N + n] : 0.0f;
    }
    __syncthreads();
    #pragma unroll 4
    for (int kc = 0; kc < 32; ++kc) {
      float av[4], bv[4];
      #pragma unroll
      for (int i = 0; i < 4; ++i) av[i] = As[ty * 4 + i][kc];
      #pragma unroll
      for (int jn = 0; jn < 4; ++jn) bv[jn] = Ws[kc][tx * 4 + jn];
      #pragma unroll
      for (int i = 0; i < 4; ++i)
        #pragma unroll
        for (int jn = 0; jn < 4; ++jn) acc[i][jn] += av[i] * bv[jn];
    }
    __syncthreads();
  }
  #pragma unroll
  for (int i = 0; i < 4; ++i) {
    int rw = m0 + ty * 4 + i;
    #pragma unroll
    for (int jn = 0; jn < 4; ++jn) {
      int col = n0 + tx * 4 + jn;
      if (col < J.N) {
        float v = acc[i][jn];
        if (J.epi == 1) v = sig_(J.bias[col] + v);
        else if (J.epi == 2) v = 0.60653065971263342f * sig_(J.bias[col] + v);
        J.C[(size_t)rw * J.N + col] = v;
      }
    }
  }
}

// -------- weight transpose+split: src fp32 [K=2048][N] -> hi/lo bf16 [Npad][2048] --------
struct TJob { const float* src; unsigned short* dh; unsigned short* dl; int N, ntn, tile_end; };
struct TJobs { TJob j[4]; };

__global__ __launch_bounds__(256) void wtrans(TJobs P) {
  __shared__ float t[64][65];
  int bx = blockIdx.x, ji = 0;
  while (bx >= P.j[ji].tile_end) ++ji;
  TJob J = P.j[ji];
  int tix = bx - (ji ? P.j[ji - 1].tile_end : 0);
  int kt = tix / J.ntn, nt = tix % J.ntn;
  int k0 = kt * 64, n0 = nt * 64;
  int tid = threadIdx.x;
  #pragma unroll
  for (int p = 0; p < 16; ++p) {
    int flat = p * 256 + tid;
    int r = flat >> 6, c = flat & 63;
    int n = n0 + c;
    t[r][c] = (n < J.N) ? J.src[(size_t)(k0 + r) * J.N + n] : 0.0f;
  }
  __syncthreads();
  #pragma unroll
  for (int p = 0; p < 8; ++p) {
    int flat = p * 256 + tid;
    int rr = flat >> 5, cc = (flat & 31) * 2;
    float w0v = t[cc][rr], w1v = t[cc + 1][rr];
    unsigned short h0 = f2bf(w0v), h1 = f2bf(w1v);
    us2v oh, ol;
    oh.x = h0; oh.y = h1;
    ol.x = f2bf(w0v - bf2f(h0));
    ol.y = f2bf(w1v - bf2f(h1));
    size_t off = (size_t)(n0 + rr) * 2048 + k0 + cc;
    *(us2v*)(J.dh + off) = oh;
    *(us2v*)(J.dl + off) = ol;
  }
}

// ------------- split-bf16 MFMA GEMM: C[M=2048,N] = A[M,K] @ Wt[N,K]^T -------------
// A fp32 (optional fused token-shift mix) split hi/lo at staging; W pre-split.
// acc = Ah*Wh + Al*Wh + Ah*Wl  (lo*lo ~2^-18 rel, dropped).
// 128x128 tile, BK=32, 4 waves (2x2), 4x4 frags of 16x16x32; LDS stride 40.
struct GJob {
  const float* A; const unsigned short* Wh; const unsigned short* Wl; float* C;
  const float* mixv; const float* shift;
  int N, K, ntn, tile_end;
};
struct GJobs { GJob j[4]; };

__global__ __launch_bounds__(256) void gemm_split(GJobs P) {
  __shared__ unsigned short Ash[128][40];
  __shared__ unsigned short Asl[128][40];
  __shared__ unsigned short Bsh[128][40];
  __shared__ unsigned short Bsl[128][40];
  int bx = blockIdx.x, ji = 0;
  while (bx >= P.j[ji].tile_end) ++ji;
  GJob J = P.j[ji];
  int tix = bx - (ji ? P.j[ji - 1].tile_end : 0);
  int mt = tix / J.ntn, nt = tix % J.ntn;
  int m0 = mt * 128, n0 = nt * 128;
  int tid = threadIdx.x;
  int lane = tid & 63, wid = tid >> 6;
  int wr = wid >> 1, wc = wid & 1;
  int l15 = lane & 15, lg = lane >> 4;
  f32x4 acc[4][4] = {};

  for (int k0 = 0; k0 < J.K; k0 += 32) {
    // ---- stage A: 128 rows x 32 k, fp32 (+mix) -> hi/lo bf16 ----
    #pragma unroll
    for (int p = 0; p < 4; ++p) {
      int flat = p * 256 + tid;
      int r = flat >> 3, kq = flat & 7;
      int m = m0 + r;
      int kk = k0 + kq * 4;
      const float* xp0 = J.A + (size_t)m * J.K + kk;
      float4 xv = *(const float4*)xp0;
      float va[4];
      if (J.mixv) {
        const float* pp = ((m & (T_ - 1)) == 0)
            ? (J.shift + (size_t)(m >> 10) * C_ + kk)
            : (xp0 - C_);
        float4 xq = *(const float4*)pp;
        float4 mv = *(const float4*)(J.mixv + kk);
        va[0] = xv.x + (xq.x - xv.x) * mv.x;
        va[1] = xv.y + (xq.y - xv.y) * mv.y;
        va[2] = xv.z + (xq.z - xv.z) * mv.z;
        va[3] = xv.w + (xq.w - xv.w) * mv.w;
      } else {
        va[0] = xv.x; va[1] = xv.y; va[2] = xv.z; va[3] = xv.w;
      }
      us4v oh, ol;
      #pragma unroll
      for (int q = 0; q < 4; ++q) {
        unsigned short h = f2bf(va[q]);
        oh[q] = h;
        ol[q] = f2bf(va[q] - bf2f(h));
      }
      *(us4v*)&Ash[r][kq * 4] = oh;
      *(us4v*)&Asl[r][kq * 4] = ol;
    }
    // ---- stage B: 128 n-rows x 32 k, hi/lo planes (already [N][K] bf16) ----
    #pragma unroll
    for (int p = 0; p < 2; ++p) {
      int flat = p * 256 + tid;
      int r = flat >> 2, ko = (flat & 3) * 8;
      size_t off = (size_t)(n0 + r) * J.K + k0 + ko;
      *(us8v*)&Bsh[r][ko] = *(const us8v*)(J.Wh + off);
      *(us8v*)&Bsl[r][ko] = *(const us8v*)(J.Wl + off);
    }
    __syncthreads();
    // ---- fragments + 3-product MFMA ----
    bf16x8 afh[4], afl[4], bwh[4], bwl[4];
    #pragma unroll
    for (int i = 0; i < 4; ++i) {
      int rr = wr * 64 + i * 16 + l15;
      afh[i] = __builtin_bit_cast(bf16x8, *(const us8v*)&Ash[rr][lg * 8]);
      afl[i] = __builtin_bit_cast(bf16x8, *(const us8v*)&Asl[rr][lg * 8]);
    }
    #pragma unroll
    for (int i = 0; i < 4; ++i) {
      int rr = wc * 64 + i * 16 + l15;
      bwh[i] = __builtin_bit_cast(bf16x8, *(const us8v*)&Bsh[rr][lg * 8]);
      bwl[i] = __builtin_bit_cast(bf16x8, *(const us8v*)&Bsl[rr][lg * 8]);
    }
    #pragma unroll
    for (int i = 0; i < 4; ++i)
      #pragma unroll
      for (int jn = 0; jn < 4; ++jn) {
        acc[i][jn] = __builtin_amdgcn_mfma_f32_16x16x32_bf16(
            afh[i], bwh[jn], acc[i][jn], 0, 0, 0);
        acc[i][jn] = __builtin_amdgcn_mfma_f32_16x16x32_bf16(
            afl[i], bwh[jn], acc[i][jn], 0, 0, 0);
        acc[i][jn] = __builtin_amdgcn_mfma_f32_16x16x32_bf16(
            afh[i], bwl[jn], acc[i][jn], 0, 0, 0);
      }
    __syncthreads();
  }
  // ---- C write: D[row=4*(lane>>4)+reg][col=lane&15]  (m89/m91-verified) ----
  int orow0 = m0 + wr * 64 + 4 * lg;
  int ocol0 = n0 + wc * 64 + l15;
  #pragma unroll
  for (int i = 0; i < 4; ++i) {
    #pragma unroll
    for (int jn = 0; jn < 4; ++jn) {
      int col = ocol0 + jn * 16;
      if (col < J.N) {
        #pragma unroll
        for (int rr = 0; rr < 4; ++rr)
          J.C[(size_t)(orow0 + i * 16 + rr) * J.N + col] = acc[i][jn][rr];
      }
    }
  }
}

// ---------------- prescan: one block per (b,t,h); LDS tree reduction ----------------
__global__ __launch_bounds__(64) void prescan(
    float* __restrict__ kio, float* __restrict__ vio,
    float* __restrict__ amat_ain, float* __restrict__ vmix_bin,
    const float* __restrict__ vfirst,
    const float* __restrict__ k_k, const float* __restrict__ k_a) {
  __shared__ float red[64];
  int bid = blockIdx.x, tid = threadIdx.x;
  int h = bid & (H_ - 1);
  size_t base = (size_t)bid * 64 + tid;
  int cc = h * 64 + tid;
  float kv = kio[base];
  float kkv = kv * k_k[cc];
  red[tid] = kkv * kkv;
  __syncthreads();
  for (int s = 32; s > 0; s >>= 1) { if (tid < s) red[tid] += red[tid + s]; __syncthreads(); }
  float nrm = fmaxf(sqrtf(red[0]), 1e-12f);
  float kkn = kkv / nrm;
  float av = amat_ain[base];
  float vmv = vmix_bin[base];
  float vv = vio[base];
  kio[base] = kv * (1.0f + (av - 1.0f) * k_a[cc]);
  vio[base] = vv + (vfirst[base] - vv) * vmv;
  amat_ain[base] = -kkn;
  vmix_bin[base] = kkn * av;
}

// ---------------- scan: one block per (b,h); thread v holds S[v][0..63] in regs ----------------
__global__ __launch_bounds__(64) void wkv_scan(
    const float* __restrict__ r, const float* __restrict__ k2,
    const float* __restrict__ w, const float* __restrict__ ain,
    const float* __restrict__ bin, const float* __restrict__ vp,
    const float* __restrict__ s0, float* __restrict__ o) {
  __shared__ float rr[64], kk[64], ww[64], aa[64], bb[64];
  int bid = blockIdx.x, v = threadIdx.x;
  int b = bid >> 5, h = bid & 31;
  float S[64];
  {
    const float* sp = s0 + ((size_t)bid * 64 + v) * 64;
    #pragma unroll
    for (int k = 0; k < 64; ++k) S[k] = sp[k];
  }
  for (int t = 0; t < T_; ++t) {
    size_t a_ = (((size_t)(b * T_ + t)) * H_ + h) * 64;
    rr[v] = r[a_ + v]; kk[v] = k2[a_ + v]; ww[v] = w[a_ + v];
    aa[v] = ain[a_ + v]; bb[v] = bin[a_ + v];
    float vt = vp[a_ + v];
    __syncthreads();
    float sa = 0.f;
    #pragma unroll
    for (int k = 0; k < 64; ++k) sa += S[k] * aa[k];
    float y = 0.f;
    #pragma unroll
    for (int k = 0; k < 64; ++k) {
      S[k] = S[k] * ww[k] + vt * kk[k] + sa * bb[k];
      y += S[k] * rr[k];
    }
    o[a_ + v] = y;
    __syncthreads();
  }
}

// ---------------- post: GroupNorm + bonus + gate; one block per (b,t,h) ----------------
__global__ __launch_bounds__(64) void post(
    const float* __restrict__ o, const float* __restrict__ r,
    const float* __restrict__ k2, const float* __restrict__ vp,
    const float* __restrict__ g, const float* __restrict__ r_k,
    const float* __restrict__ lnw, const float* __restrict__ lnb,
    float* __restrict__ afin) {
  __shared__ float red[64];
  int bid = blockIdx.x, tid = threadIdx.x;
  int h = bid & 31;
  size_t base = (size_t)bid * 64 + tid;
  int cc = h * 64 + tid;
  float ov = o[base];
  red[tid] = ov; __syncthreads();
  for (int s = 32; s > 0; s >>= 1) { if (tid < s) red[tid] += red[tid + s]; __syncthreads(); }
  float mu = red[0] * (1.0f / 64.0f);
  __syncthreads();
  float dv = ov - mu;
  red[tid] = dv * dv; __syncthreads();
  for (int s = 32; s > 0; s >>= 1) { if (tid < s) red[tid] += red[tid + s]; __syncthreads(); }
  float var = red[0] * (1.0f / 64.0f);
  __syncthreads();
  float on = dv * rsqrtf(var + 6.4e-4f) * lnw[cc] + lnb[cc];
  float pr = r[base] * k2[base] * r_k[cc];
  red[tid] = pr; __syncthreads();
  for (int s = 32; s > 0; s >>= 1) { if (tid < s) red[tid] += red[tid + s]; __syncthreads(); }
  float dot = red[0];
  float val = (on + dot * vp[base]) * g[base];
  afin[base] = val;
}

// ---------------- host ----------------
static constexpr size_t KB = 1024;
// fp32 [B,T,C] buffers are 16384 KiB each.
static constexpr size_t O_R    = 0;        // [G1a -> post]; W_ot hi/lo reuse after post
static constexpr size_t O_K    = 16384;    // k [G1a], k2 in-place [prescan -> post]
static constexpr size_t O_V    = 32768;    // v [G1a], v' in-place [prescan -> post]
static constexpr size_t O_WDEC = 49152;    // w decay [G2 -> scan]
static constexpr size_t O_AMAT = 65536;    // amat [G2] -> ain [prescan] -> o [scan -> post]
static constexpr size_t O_VMIX = 81920;    // vmix [G2] -> bin [prescan] -> afin [post -> G3]
static constexpr size_t O_HW   = 98304;    // 2048x64  fp32 = 512 KiB
static constexpr size_t O_HA   = 98816;
static constexpr size_t O_HV   = 99328;    // 2048x32 = 256 KiB
static constexpr size_t O_HG   = 99584;    // 2048x128 = 1024 KiB -> end 100608 KiB
static constexpr size_t O_AIN  = O_AMAT;
static constexpr size_t O_O    = O_AMAT;
static constexpr size_t O_BIN  = O_VMIX;
static constexpr size_t O_AFIN = O_VMIX;
// transposed hi/lo bf16 planes (each big plane 8192 KiB = 2048x2048x2B):
//   pre-G1a: W_r/W_k/W_v fill the dead WDEC/AMAT/VMIX regions exactly.
static constexpr size_t O_WRT_H = 49152, O_WRT_L = 57344;
static constexpr size_t O_WKT_H = 65536, O_WKT_L = 73728;
static constexpr size_t O_WVT_H = 81920, O_WVT_L = 90112;   // ends 98304
//   post-G1a (over dead W_rt, gone before G2 writes O_WDEC): small planes 512 KiB each.
static constexpr size_t O_W1T_H = 49152, O_W1T_L = 49664;
static constexpr size_t O_A1T_H = 50176, O_A1T_L = 50688;
static constexpr size_t O_V1T_H = 51200, O_V1T_L = 51712;
static constexpr size_t O_G1T_H = 52224, O_G1T_L = 52736;   // ends 53248
//   post-`post` (over dead r):
static constexpr size_t O_WOT_H = 0, O_WOT_L = 8192;

extern "C" void kernel_launch(void* const* d_in, const int* in_sizes, int n_in,
                              void* d_out, int out_size, void* d_ws, size_t ws_size,
                              hipStream_t stream) {
  const float* x      = (const float*)d_in[0];
  const float* vfirst = (const float*)d_in[1];
  const float* shift  = (const float*)d_in[2];
  const float* wkv0   = (const float*)d_in[3];
  const float* x_r = (const float*)d_in[4];
  const float* x_w = (const float*)d_in[5];
  const float* x_k = (const float*)d_in[6];
  const float* x_v = (const float*)d_in[7];
  const float* x_a = (const float*)d_in[8];
  const float* x_g = (const float*)d_in[9];
  const float* w0 = (const float*)d_in[10];
  const float* w1 = (const float*)d_in[11];
  const float* w2 = (const float*)d_in[12];
  const float* a0 = (const float*)d_in[13];
  const float* a1 = (const float*)d_in[14];
  const float* a2 = (const float*)d_in[15];
  const float* v0 = (const float*)d_in[16];
  const float* v1 = (const float*)d_in[17];
  const float* v2 = (const float*)d_in[18];
  const float* g1 = (const float*)d_in[19];
  const float* g2 = (const float*)d_in[20];
  const float* k_k = (const float*)d_in[21];
  const float* k_a = (const float*)d_in[22];
  const float* r_k = (const float*)d_in[23];
  const float* W_r = (const float*)d_in[24];
  const float* W_k = (const float*)d_in[25];
  const float* W_v = (const float*)d_in[26];
  const float* W_o = (const float*)d_in[27];
  const float* ln_w = (const float*)d_in[28];
  const float* ln_b = (const float*)d_in[29];

  char* ws = (char*)d_ws;
  auto F = [&](size_t kb) { return (float*)(ws + kb * KB); };
  auto U = [&](size_t kb) { return (unsigned short*)(ws + kb * KB); };
  float* outp = (float*)d_out;

  // T1a: transpose+split the three big weights into dead WDEC/AMAT/VMIX regions.
  {
    TJobs TG{};
    int cum = 0, i = 0;
    auto addT = [&](const float* src, size_t hkb, size_t lkb) {
      cum += 32 * 32;
      TG.j[i++] = TJob{src, U(hkb), U(lkb), 2048, 32, cum};
    };
    addT(W_r, O_WRT_H, O_WRT_L);
    addT(W_k, O_WKT_H, O_WKT_L);
    addT(W_v, O_WVT_H, O_WVT_L);
    wtrans<<<dim3(cum), dim3(256), 0, stream>>>(TG);
  }

  // G1a (split MFMA): r, k, v with fused token-shift mixes.
  {
    GJobs G{};
    int cum = 0, i = 0;
    auto add = [&](size_t hkb, size_t lkb, float* Cp, const float* mixv) {
      cum += 16 * 16;
      G.j[i++] = GJob{x, U(hkb), U(lkb), Cp, mixv, shift, 2048, 2048, 16, cum};
    };
    add(O_WRT_H, O_WRT_L, F(O_R), x_r);
    add(O_WKT_H, O_WKT_L, F(O_K), x_k);
    add(O_WVT_H, O_WVT_L, F(O_V), x_v);
    gemm_split<<<dim3(cum), dim3(256), 0, stream>>>(G);
  }

  // T1b: transpose+split small LoRA-down weights over dead W_rt space.
  {
    TJobs TG{};
    int cum = 0, i = 0;
    auto addT = [&](const float* src, size_t hkb, size_t lkb, int N) {
      cum += 32 * 2;                      // Npad = 128
      TG.j[i++] = TJob{src, U(hkb), U(lkb), N, 2, cum};
    };
    addT(w1, O_W1T_H, O_W1T_L, 64);
    addT(a1, O_A1T_H, O_A1T_L, 64);
    addT(v1, O_V1T_H, O_V1T_L, 32);
    addT(g1, O_G1T_H, O_G1T_L, 128);
    wtrans<<<dim3(cum), dim3(256), 0, stream>>>(TG);
  }

  // G1b (split MFMA): the four LoRA-down projections.
  {
    GJobs G{};
    int cum = 0, i = 0;
    auto add = [&](size_t hkb, size_t lkb, float* Cp, const float* mixv, int N) {
      cum += 16;                          // ntn = 1 (Npad 128)
      G.j[i++] = GJob{x, U(hkb), U(lkb), Cp, mixv, shift, N, 2048, 1, cum};
    };
    add(O_W1T_H, O_W1T_L, F(O_HW), x_w, 64);
    add(O_A1T_H, O_A1T_L, F(O_HA), x_a, 64);
    add(O_V1T_H, O_V1T_L, F(O_HV), x_v, 32);
    add(O_G1T_H, O_G1T_L, F(O_HG), x_g, 128);
    gemm_split<<<dim3(cum), dim3(256), 0, stream>>>(G);
  }

  // G2 (fp32 oracle): LoRA-up with fused activations/epilogues.
  {
    Jobs G{};
    int cum = 0, i = 0;
    auto add = [&](const float* A, const float* W, float* C, const float* bias,
                   int K, int aact, int epi) {
      cum += 32 * 32;
      G.j[i++] = Job{A, W, C, bias, nullptr, nullptr, nullptr, 2048, K, 32, aact, epi, cum};
    };
    add(F(O_HW), w2, F(O_WDEC), w0, 64, 1, 2);   // w = e^-0.5*sigmoid(w0 + tanh(hw)@w2)
    add(F(O_HA), a2, F(O_AMAT), a0, 64, 0, 1);   // a = sigmoid(a0 + ha@a2)
    add(F(O_HV), v2, F(O_VMIX), v0, 32, 0, 1);   // vmix = sigmoid(v0 + hv@v2)
    add(F(O_HG), g2, outp,     nullptr, 128, 2, 0); // g = sigmoid(hg)@g2 (in d_out)
    gemm_oracle<<<dim3(cum), dim3(256), 0, stream>>>(G);
  }

  // prescan: kk-norm; k->k2, v->v', amat->a_in, vmix->b_in.
  prescan<<<dim3(65536), dim3(64), 0, stream>>>(F(O_K), F(O_V), F(O_AMAT), F(O_VMIX),
                                                vfirst, k_k, k_a);

  // scan: 64 blocks (b,h), S in registers, o overwrites ain region.
  wkv_scan<<<dim3(64), dim3(64), 0, stream>>>(F(O_R), F(O_K), F(O_WDEC), F(O_AIN),
                                              F(O_BIN), F(O_V), wkv0, F(O_O));

  // post: GroupNorm + bonus + gate -> afin.
  post<<<dim3(65536), dim3(64), 0, stream>>>(F(O_O), F(O_R), F(O_K), F(O_V),
                                             outp, r_k, ln_w, ln_b, F(O_AFIN));

  // T2: W_o transpose+split into dead r region, then G3 (split MFMA): out = afin @ W_o.
  {
    TJobs TO{};
    TO.j[0] = TJob{W_o, U(O_WOT_H), U(O_WOT_L), 2048, 32, 1024};
    wtrans<<<dim3(1024), dim3(256), 0, stream>>>(TO);
    GJobs G{};
    G.j[0] = GJob{F(O_AFIN), U(O_WOT_H), U(O_WOT_L), outp, nullptr, nullptr,
                  2048, 2048, 16, 256};
    gemm_split<<<dim3(256), dim3(256), 0, stream>>>(G);
  }

  (void)in_sizes; (void)n_in; (void)out_size; (void)ws_size;
}

// Round 3
// 1300.367 us; speedup vs baseline: 2.7638x; 1.5477x over previous
//
#include <hip/hip_runtime.h>
#include <cstdint>
#include <cstddef>

// RWKV-7 Tmix forward, MI355X gfx950 — ROUND 7: parallel+prefetched WKV scan.
// Round-6 result: wkv_scan = 1163 µs (58%), 2730 cyc/step, 1 wave/CU, pure
// HBM-latency bound. Fix: (a) LDS chunk-staging (32 steps, double-buffered,
// async global_load_lds prefetch issued before compute); (b) 4-way v-row
// parallelism per (b,h): 256 thr/block, lane=(v_local,k_quarter), 16 S-regs
// per lane, sa/y finished with 2 intra-quad ds_swizzle butterflies.
// GEMMs: split-bf16 MFMA (round-6, verified). Workspace unchanged (100608 KiB).

#define DI __device__ __forceinline__
static constexpr int T_ = 1024, C_ = 2048, H_ = 32;

typedef __attribute__((ext_vector_type(8))) __bf16 bf16x8;
typedef __attribute__((ext_vector_type(4))) float f32x4;
typedef __attribute__((ext_vector_type(8))) unsigned short us8v;
typedef __attribute__((ext_vector_type(4))) unsigned short us4v;
typedef __attribute__((ext_vector_type(2))) unsigned short us2v;

DI float sig_(float z) { return 1.0f / (1.0f + expf(-z)); }

DI unsigned short f2bf(float f) {           // round-to-nearest-even f32 -> bf16
  union { float f; uint32_t u; } v; v.f = f;
  uint32_t u = v.u;
  return (unsigned short)((u + 0x7FFFu + ((u >> 16) & 1u)) >> 16);
}
DI float bf2f(unsigned short h) {
  union { uint32_t u; float f; } v; v.u = ((uint32_t)h) << 16;
  return v.f;
}

// intra-quad butterflies (lanes xor 1 / xor 2): ds_swizzle BitMode offsets.
DI float qswap1(float x) {
  return __int_as_float(__builtin_amdgcn_ds_swizzle(__float_as_int(x), 0x041F));
}
DI float qswap2(float x) {
  return __int_as_float(__builtin_amdgcn_ds_swizzle(__float_as_int(x), 0x081F));
}

// async global -> LDS DMA, 16 B per lane (dest = wave-uniform base + lane*16).
DI void gload16(const float* g, float* l) {
  __builtin_amdgcn_global_load_lds(
      (const __attribute__((address_space(1))) uint32_t*)g,
      (__attribute__((address_space(3))) uint32_t*)l, 16, 0, 0);
}

// ---------------- fp32 oracle GEMM (kept for G2: K<=128 LoRA-up jobs) ----------------
struct Job {
  const float* A; const float* W; float* C; const float* bias;
  const float* mixv; const float* x; const float* shift;
  int N, K, ntn, aact, epi, tile_end;
};
struct Jobs { Job j[7]; };

__global__ __launch_bounds__(256) void gemm_oracle(Jobs P) {
  __shared__ float As[64][33];
  __shared__ float Ws[32][65];
  int bx = blockIdx.x, ji = 0;
  while (bx >= P.j[ji].tile_end) ++ji;
  Job J = P.j[ji];
  int tix = bx - (ji ? P.j[ji - 1].tile_end : 0);
  int mt = tix / J.ntn, nt = tix % J.ntn;
  int m0 = mt * 64, n0 = nt * 64;
  int tid = threadIdx.x, tx = tid & 15, ty = tid >> 4;
  float acc[4][4] = {};
  for (int k0 = 0; k0 < J.K; k0 += 32) {
    #pragma unroll
    for (int p = 0; p < 8; ++p) {
      int idx = p * 256 + tid;
      int r = idx >> 5, kc = idx & 31;
      int m = m0 + r, k = k0 + kc;
      float a;
      if (J.mixv) {
        float xv = J.x[(size_t)m * C_ + k];
        int t = m & (T_ - 1);
        float xp = (t == 0) ? J.shift[(size_t)(m >> 10) * C_ + k]
                            : J.x[(size_t)(m - 1) * C_ + k];
        a = xv + (xp - xv) * J.mixv[k];
      } else {
        a = J.A[(size_t)m * J.K + k];
        if (J.aact == 1) a = tanhf(a);
        else if (J.aact == 2) a = sig_(a);
      }
      As[r][kc] = a;
    }
    #pragma unroll
    for (int p = 0; p < 8; ++p) {
      int idx = p * 256 + tid;
      int kr = idx >> 6, nc = idx & 63;
      int n = n0 + nc;
      Ws[kr][nc] = (n < J.N) ? J.W[(size_t)(k0 + kr) * J.N + n] : 0.0f;
    }
    __syncthreads();
    #pragma unroll 4
    for (int kc = 0; kc < 32; ++kc) {
      float av[4], bv[4];
      #pragma unroll
      for (int i = 0; i < 4; ++i) av[i] = As[ty * 4 + i][kc];
      #pragma unroll
      for (int jn = 0; jn < 4; ++jn) bv[jn] = Ws[kc][tx * 4 + jn];
      #pragma unroll
      for (int i = 0; i < 4; ++i)
        #pragma unroll
        for (int jn = 0; jn < 4; ++jn) acc[i][jn] += av[i] * bv[jn];
    }
    __syncthreads();
  }
  #pragma unroll
  for (int i = 0; i < 4; ++i) {
    int rw = m0 + ty * 4 + i;
    #pragma unroll
    for (int jn = 0; jn < 4; ++jn) {
      int col = n0 + tx * 4 + jn;
      if (col < J.N) {
        float v = acc[i][jn];
        if (J.epi == 1) v = sig_(J.bias[col] + v);
        else if (J.epi == 2) v = 0.60653065971263342f * sig_(J.bias[col] + v);
        J.C[(size_t)rw * J.N + col] = v;
      }
    }
  }
}

// -------- weight transpose+split: src fp32 [K=2048][N] -> hi/lo bf16 [Npad][2048] --------
struct TJob { const float* src; unsigned short* dh; unsigned short* dl; int N, ntn, tile_end; };
struct TJobs { TJob j[4]; };

__global__ __launch_bounds__(256) void wtrans(TJobs P) {
  __shared__ float t[64][65];
  int bx = blockIdx.x, ji = 0;
  while (bx >= P.j[ji].tile_end) ++ji;
  TJob J = P.j[ji];
  int tix = bx - (ji ? P.j[ji - 1].tile_end : 0);
  int kt = tix / J.ntn, nt = tix % J.ntn;
  int k0 = kt * 64, n0 = nt * 64;
  int tid = threadIdx.x;
  #pragma unroll
  for (int p = 0; p < 16; ++p) {
    int flat = p * 256 + tid;
    int r = flat >> 6, c = flat & 63;
    int n = n0 + c;
    t[r][c] = (n < J.N) ? J.src[(size_t)(k0 + r) * J.N + n] : 0.0f;
  }
  __syncthreads();
  #pragma unroll
  for (int p = 0; p < 8; ++p) {
    int flat = p * 256 + tid;
    int rr = flat >> 5, cc = (flat & 31) * 2;
    float w0v = t[cc][rr], w1v = t[cc + 1][rr];
    unsigned short h0 = f2bf(w0v), h1 = f2bf(w1v);
    us2v oh, ol;
    oh.x = h0; oh.y = h1;
    ol.x = f2bf(w0v - bf2f(h0));
    ol.y = f2bf(w1v - bf2f(h1));
    size_t off = (size_t)(n0 + rr) * 2048 + k0 + cc;
    *(us2v*)(J.dh + off) = oh;
    *(us2v*)(J.dl + off) = ol;
  }
}

// ------------- split-bf16 MFMA GEMM: C[M=2048,N] = A[M,K] @ Wt[N,K]^T -------------
struct GJob {
  const float* A; const unsigned short* Wh; const unsigned short* Wl; float* C;
  const float* mixv; const float* shift;
  int N, K, ntn, tile_end;
};
struct GJobs { GJob j[4]; };

__global__ __launch_bounds__(256) void gemm_split(GJobs P) {
  __shared__ unsigned short Ash[128][40];
  __shared__ unsigned short Asl[128][40];
  __shared__ unsigned short Bsh[128][40];
  __shared__ unsigned short Bsl[128][40];
  int bx = blockIdx.x, ji = 0;
  while (bx >= P.j[ji].tile_end) ++ji;
  GJob J = P.j[ji];
  int tix = bx - (ji ? P.j[ji - 1].tile_end : 0);
  int mt = tix / J.ntn, nt = tix % J.ntn;
  int m0 = mt * 128, n0 = nt * 128;
  int tid = threadIdx.x;
  int lane = tid & 63, wid = tid >> 6;
  int wr = wid >> 1, wc = wid & 1;
  int l15 = lane & 15, lg = lane >> 4;
  f32x4 acc[4][4] = {};

  for (int k0 = 0; k0 < J.K; k0 += 32) {
    #pragma unroll
    for (int p = 0; p < 4; ++p) {
      int flat = p * 256 + tid;
      int r = flat >> 3, kq = flat & 7;
      int m = m0 + r;
      int kk = k0 + kq * 4;
      const float* xp0 = J.A + (size_t)m * J.K + kk;
      float4 xv = *(const float4*)xp0;
      float va[4];
      if (J.mixv) {
        const float* pp = ((m & (T_ - 1)) == 0)
            ? (J.shift + (size_t)(m >> 10) * C_ + kk)
            : (xp0 - C_);
        float4 xq = *(const float4*)pp;
        float4 mv = *(const float4*)(J.mixv + kk);
        va[0] = xv.x + (xq.x - xv.x) * mv.x;
        va[1] = xv.y + (xq.y - xv.y) * mv.y;
        va[2] = xv.z + (xq.z - xv.z) * mv.z;
        va[3] = xv.w + (xq.w - xv.w) * mv.w;
      } else {
        va[0] = xv.x; va[1] = xv.y; va[2] = xv.z; va[3] = xv.w;
      }
      us4v oh, ol;
      #pragma unroll
      for (int q = 0; q < 4; ++q) {
        unsigned short h = f2bf(va[q]);
        oh[q] = h;
        ol[q] = f2bf(va[q] - bf2f(h));
      }
      *(us4v*)&Ash[r][kq * 4] = oh;
      *(us4v*)&Asl[r][kq * 4] = ol;
    }
    #pragma unroll
    for (int p = 0; p < 2; ++p) {
      int flat = p * 256 + tid;
      int r = flat >> 2, ko = (flat & 3) * 8;
      size_t off = (size_t)(n0 + r) * J.K + k0 + ko;
      *(us8v*)&Bsh[r][ko] = *(const us8v*)(J.Wh + off);
      *(us8v*)&Bsl[r][ko] = *(const us8v*)(J.Wl + off);
    }
    __syncthreads();
    bf16x8 afh[4], afl[4], bwh[4], bwl[4];
    #pragma unroll
    for (int i = 0; i < 4; ++i) {
      int rr = wr * 64 + i * 16 + l15;
      afh[i] = __builtin_bit_cast(bf16x8, *(const us8v*)&Ash[rr][lg * 8]);
      afl[i] = __builtin_bit_cast(bf16x8, *(const us8v*)&Asl[rr][lg * 8]);
    }
    #pragma unroll
    for (int i = 0; i < 4; ++i) {
      int rr = wc * 64 + i * 16 + l15;
      bwh[i] = __builtin_bit_cast(bf16x8, *(const us8v*)&Bsh[rr][lg * 8]);
      bwl[i] = __builtin_bit_cast(bf16x8, *(const us8v*)&Bsl[rr][lg * 8]);
    }
    #pragma unroll
    for (int i = 0; i < 4; ++i)
      #pragma unroll
      for (int jn = 0; jn < 4; ++jn) {
        acc[i][jn] = __builtin_amdgcn_mfma_f32_16x16x32_bf16(
            afh[i], bwh[jn], acc[i][jn], 0, 0, 0);
        acc[i][jn] = __builtin_amdgcn_mfma_f32_16x16x32_bf16(
            afl[i], bwh[jn], acc[i][jn], 0, 0, 0);
        acc[i][jn] = __builtin_amdgcn_mfma_f32_16x16x32_bf16(
            afh[i], bwl[jn], acc[i][jn], 0, 0, 0);
      }
    __syncthreads();
  }
  int orow0 = m0 + wr * 64 + 4 * lg;
  int ocol0 = n0 + wc * 64 + l15;
  #pragma unroll
  for (int i = 0; i < 4; ++i) {
    #pragma unroll
    for (int jn = 0; jn < 4; ++jn) {
      int col = ocol0 + jn * 16;
      if (col < J.N) {
        #pragma unroll
        for (int rr = 0; rr < 4; ++rr)
          J.C[(size_t)(orow0 + i * 16 + rr) * J.N + col] = acc[i][jn][rr];
      }
    }
  }
}

// ---------------- prescan: one block per (b,t,h); LDS tree reduction ----------------
__global__ __launch_bounds__(64) void prescan(
    float* __restrict__ kio, float* __restrict__ vio,
    float* __restrict__ amat_ain, float* __restrict__ vmix_bin,
    const float* __restrict__ vfirst,
    const float* __restrict__ k_k, const float* __restrict__ k_a) {
  __shared__ float red[64];
  int bid = blockIdx.x, tid = threadIdx.x;
  int h = bid & (H_ - 1);
  size_t base = (size_t)bid * 64 + tid;
  int cc = h * 64 + tid;
  float kv = kio[base];
  float kkv = kv * k_k[cc];
  red[tid] = kkv * kkv;
  __syncthreads();
  for (int s = 32; s > 0; s >>= 1) { if (tid < s) red[tid] += red[tid + s]; __syncthreads(); }
  float nrm = fmaxf(sqrtf(red[0]), 1e-12f);
  float kkn = kkv / nrm;
  float av = amat_ain[base];
  float vmv = vmix_bin[base];
  float vv = vio[base];
  kio[base] = kv * (1.0f + (av - 1.0f) * k_a[cc]);
  vio[base] = vv + (vfirst[base] - vv) * vmv;
  amat_ain[base] = -kkn;
  vmix_bin[base] = kkn * av;
}

// ------- wkv scan v2: 64 blocks (b,h) x 256 threads (4 waves = 4 v-slices) -------
// Lane (within wave): vl = lane>>2 (16 v-rows per wave), kq = lane&3 (k-quarter).
// Each lane owns S[v][kq*16 .. kq*16+16) in 16 VGPRs. sa/y finished with two
// intra-quad ds_swizzle butterflies. Inputs chunk-staged (CH=32 steps) into
// double-buffered LDS via async global_load_lds, prefetched one chunk ahead.
static constexpr int CH = 32;

__global__ __launch_bounds__(256) void wkv_scan4(
    const float* __restrict__ r, const float* __restrict__ k2,
    const float* __restrict__ w, const float* __restrict__ ain,
    const float* __restrict__ bin, const float* __restrict__ vp,
    const float* __restrict__ sInit, float* __restrict__ o) {
  __shared__ float lds[2][6][CH][64];      // 96 KiB
  int bid = blockIdx.x;
  int b = bid >> 5, h = bid & 31;
  int tid = threadIdx.x;
  int q = tid >> 6, lane = tid & 63;
  int vl = lane >> 2, kq = lane & 3;
  int v = q * 16 + vl;
  int kb = kq * 16;
  size_t bh = (size_t)(b * T_) * 2048 + (size_t)h * 64;   // float offset at t=0

  float S[16];
  {
    const float* sp = sInit + (((size_t)(b * H_ + h) * 64 + v) * 64) + kb;
    #pragma unroll
    for (int i = 0; i < 16; i += 4) {
      float4 sv = *(const float4*)(sp + i);
      S[i] = sv.x; S[i + 1] = sv.y; S[i + 2] = sv.z; S[i + 3] = sv.w;
    }
  }

  const float* arr0 = r; const float* arr1 = k2; const float* arr2 = w;
  const float* arr3 = ain; const float* arr4 = bin; const float* arr5 = vp;

  // stage: wave q loads t-rows [q*8, q*8+8) of each array (2 x 4-row DMA each).
  auto stage = [&](int buf, int t0) {
    #pragma unroll
    for (int jj = 0; jj < 2; ++jj) {
      int s4 = q * 8 + jj * 4;
      size_t gofs = bh + (size_t)(t0 + s4 + (lane >> 4)) * 2048 + (lane & 15) * 4;
      gload16(arr0 + gofs, &lds[buf][0][s4][0]);
      gload16(arr1 + gofs, &lds[buf][1][s4][0]);
      gload16(arr2 + gofs, &lds[buf][2][s4][0]);
      gload16(arr3 + gofs, &lds[buf][3][s4][0]);
      gload16(arr4 + gofs, &lds[buf][4][s4][0]);
      gload16(arr5 + gofs, &lds[buf][5][s4][0]);
    }
  };

  stage(0, 0);
  asm volatile("s_waitcnt vmcnt(0)" ::: "memory");
  __syncthreads();

  for (int c = 0; c < T_ / CH; ++c) {
    int cur = c & 1;
    if (c + 1 < T_ / CH) stage(cur ^ 1, (c + 1) * CH);
    int t0 = c * CH;
    #pragma unroll 4
    for (int s = 0; s < CH; ++s) {
      // sa partial over this lane's 16 k's (4 chains), then quad butterfly.
      float aa[16];
      #pragma unroll
      for (int i = 0; i < 16; i += 4)
        *(float4*)&aa[i] = *(const float4*)&lds[cur][3][s][kb + i];
      float p0 = 0.f, p1 = 0.f, p2 = 0.f, p3 = 0.f;
      #pragma unroll
      for (int i = 0; i < 16; i += 4) {
        p0 = fmaf(S[i], aa[i], p0);
        p1 = fmaf(S[i + 1], aa[i + 1], p1);
        p2 = fmaf(S[i + 2], aa[i + 2], p2);
        p3 = fmaf(S[i + 3], aa[i + 3], p3);
      }
      float sa = (p0 + p1) + (p2 + p3);
      sa += qswap1(sa);
      sa += qswap2(sa);
      float vt = lds[cur][5][s][v];
      float ww[16], kk[16], bb[16], rr[16];
      #pragma unroll
      for (int i = 0; i < 16; i += 4) {
        *(float4*)&ww[i] = *(const float4*)&lds[cur][2][s][kb + i];
        *(float4*)&kk[i] = *(const float4*)&lds[cur][1][s][kb + i];
        *(float4*)&bb[i] = *(const float4*)&lds[cur][4][s][kb + i];
        *(float4*)&rr[i] = *(const float4*)&lds[cur][0][s][kb + i];
      }
      float y0 = 0.f, y1 = 0.f, y2 = 0.f, y3 = 0.f;
      #pragma unroll
      for (int i = 0; i < 16; i += 4) {
        S[i]     = fmaf(S[i],     ww[i],     fmaf(vt, kk[i],     sa * bb[i]));
        S[i + 1] = fmaf(S[i + 1], ww[i + 1], fmaf(vt, kk[i + 1], sa * bb[i + 1]));
        S[i + 2] = fmaf(S[i + 2], ww[i + 2], fmaf(vt, kk[i + 2], sa * bb[i + 2]));
        S[i + 3] = fmaf(S[i + 3], ww[i + 3], fmaf(vt, kk[i + 3], sa * bb[i + 3]));
        y0 = fmaf(S[i], rr[i], y0);
        y1 = fmaf(S[i + 1], rr[i + 1], y1);
        y2 = fmaf(S[i + 2], rr[i + 2], y2);
        y3 = fmaf(S[i + 3], rr[i + 3], y3);
      }
      float y = (y0 + y1) + (y2 + y3);
      y += qswap1(y);
      y += qswap2(y);
      if (kq == 0) o[bh + (size_t)(t0 + s) * 2048 + v] = y;
    }
    asm volatile("s_waitcnt vmcnt(0)" ::: "memory");
    __syncthreads();
  }
}

// ---------------- post: GroupNorm + bonus + gate; one block per (b,t,h) ----------------
__global__ __launch_bounds__(64) void post(
    const float* __restrict__ o, const float* __restrict__ r,
    const float* __restrict__ k2, const float* __restrict__ vp,
    const float* __restrict__ g, const float* __restrict__ r_k,
    const float* __restrict__ lnw, const float* __restrict__ lnb,
    float* __restrict__ afin) {
  __shared__ float red[64];
  int bid = blockIdx.x, tid = threadIdx.x;
  int h = bid & 31;
  size_t base = (size_t)bid * 64 + tid;
  int cc = h * 64 + tid;
  float ov = o[base];
  red[tid] = ov; __syncthreads();
  for (int s = 32; s > 0; s >>= 1) { if (tid < s) red[tid] += red[tid + s]; __syncthreads(); }
  float mu = red[0] * (1.0f / 64.0f);
  __syncthreads();
  float dv = ov - mu;
  red[tid] = dv * dv; __syncthreads();
  for (int s = 32; s > 0; s >>= 1) { if (tid < s) red[tid] += red[tid + s]; __syncthreads(); }
  float var = red[0] * (1.0f / 64.0f);
  __syncthreads();
  float on = dv * rsqrtf(var + 6.4e-4f) * lnw[cc] + lnb[cc];
  float pr = r[base] * k2[base] * r_k[cc];
  red[tid] = pr; __syncthreads();
  for (int s = 32; s > 0; s >>= 1) { if (tid < s) red[tid] += red[tid + s]; __syncthreads(); }
  float dot = red[0];
  float val = (on + dot * vp[base]) * g[base];
  afin[base] = val;
}

// ---------------- host ----------------
static constexpr size_t KB = 1024;
static constexpr size_t O_R    = 0;
static constexpr size_t O_K    = 16384;
static constexpr size_t O_V    = 32768;
static constexpr size_t O_WDEC = 49152;
static constexpr size_t O_AMAT = 65536;
static constexpr size_t O_VMIX = 81920;
static constexpr size_t O_HW   = 98304;
static constexpr size_t O_HA   = 98816;
static constexpr size_t O_HV   = 99328;
static constexpr size_t O_HG   = 99584;
static constexpr size_t O_AIN  = O_AMAT;
static constexpr size_t O_O    = O_AMAT;
static constexpr size_t O_BIN  = O_VMIX;
static constexpr size_t O_AFIN = O_VMIX;
static constexpr size_t O_WRT_H = 49152, O_WRT_L = 57344;
static constexpr size_t O_WKT_H = 65536, O_WKT_L = 73728;
static constexpr size_t O_WVT_H = 81920, O_WVT_L = 90112;
static constexpr size_t O_W1T_H = 49152, O_W1T_L = 49664;
static constexpr size_t O_A1T_H = 50176, O_A1T_L = 50688;
static constexpr size_t O_V1T_H = 51200, O_V1T_L = 51712;
static constexpr size_t O_G1T_H = 52224, O_G1T_L = 52736;
static constexpr size_t O_WOT_H = 0, O_WOT_L = 8192;

extern "C" void kernel_launch(void* const* d_in, const int* in_sizes, int n_in,
                              void* d_out, int out_size, void* d_ws, size_t ws_size,
                              hipStream_t stream) {
  const float* x      = (const float*)d_in[0];
  const float* vfirst = (const float*)d_in[1];
  const float* shift  = (const float*)d_in[2];
  const float* wkv0   = (const float*)d_in[3];
  const float* x_r = (const float*)d_in[4];
  const float* x_w = (const float*)d_in[5];
  const float* x_k = (const float*)d_in[6];
  const float* x_v = (const float*)d_in[7];
  const float* x_a = (const float*)d_in[8];
  const float* x_g = (const float*)d_in[9];
  const float* w0 = (const float*)d_in[10];
  const float* w1 = (const float*)d_in[11];
  const float* w2 = (const float*)d_in[12];
  const float* a0 = (const float*)d_in[13];
  const float* a1 = (const float*)d_in[14];
  const float* a2 = (const float*)d_in[15];
  const float* v0 = (const float*)d_in[16];
  const float* v1 = (const float*)d_in[17];
  const float* v2 = (const float*)d_in[18];
  const float* g1 = (const float*)d_in[19];
  const float* g2 = (const float*)d_in[20];
  const float* k_k = (const float*)d_in[21];
  const float* k_a = (const float*)d_in[22];
  const float* r_k = (const float*)d_in[23];
  const float* W_r = (const float*)d_in[24];
  const float* W_k = (const float*)d_in[25];
  const float* W_v = (const float*)d_in[26];
  const float* W_o = (const float*)d_in[27];
  const float* ln_w = (const float*)d_in[28];
  const float* ln_b = (const float*)d_in[29];

  char* ws = (char*)d_ws;
  auto F = [&](size_t kb) { return (float*)(ws + kb * KB); };
  auto U = [&](size_t kb) { return (unsigned short*)(ws + kb * KB); };
  float* outp = (float*)d_out;

  // T1a: transpose+split the three big weights into dead WDEC/AMAT/VMIX regions.
  {
    TJobs TG{};
    int cum = 0, i = 0;
    auto addT = [&](const float* src, size_t hkb, size_t lkb) {
      cum += 32 * 32;
      TG.j[i++] = TJob{src, U(hkb), U(lkb), 2048, 32, cum};
    };
    addT(W_r, O_WRT_H, O_WRT_L);
    addT(W_k, O_WKT_H, O_WKT_L);
    addT(W_v, O_WVT_H, O_WVT_L);
    wtrans<<<dim3(cum), dim3(256), 0, stream>>>(TG);
  }

  // G1a (split MFMA): r, k, v with fused token-shift mixes.
  {
    GJobs G{};
    int cum = 0, i = 0;
    auto add = [&](size_t hkb, size_t lkb, float* Cp, const float* mixv) {
      cum += 16 * 16;
      G.j[i++] = GJob{x, U(hkb), U(lkb), Cp, mixv, shift, 2048, 2048, 16, cum};
    };
    add(O_WRT_H, O_WRT_L, F(O_R), x_r);
    add(O_WKT_H, O_WKT_L, F(O_K), x_k);
    add(O_WVT_H, O_WVT_L, F(O_V), x_v);
    gemm_split<<<dim3(cum), dim3(256), 0, stream>>>(G);
  }

  // T1b: transpose+split small LoRA-down weights over dead W_rt space.
  {
    TJobs TG{};
    int cum = 0, i = 0;
    auto addT = [&](const float* src, size_t hkb, size_t lkb, int N) {
      cum += 32 * 2;
      TG.j[i++] = TJob{src, U(hkb), U(lkb), N, 2, cum};
    };
    addT(w1, O_W1T_H, O_W1T_L, 64);
    addT(a1, O_A1T_H, O_A1T_L, 64);
    addT(v1, O_V1T_H, O_V1T_L, 32);
    addT(g1, O_G1T_H, O_G1T_L, 128);
    wtrans<<<dim3(cum), dim3(256), 0, stream>>>(TG);
  }

  // G1b (split MFMA): the four LoRA-down projections.
  {
    GJobs G{};
    int cum = 0, i = 0;
    auto add = [&](size_t hkb, size_t lkb, float* Cp, const float* mixv, int N) {
      cum += 16;
      G.j[i++] = GJob{x, U(hkb), U(lkb), Cp, mixv, shift, N, 2048, 1, cum};
    };
    add(O_W1T_H, O_W1T_L, F(O_HW), x_w, 64);
    add(O_A1T_H, O_A1T_L, F(O_HA), x_a, 64);
    add(O_V1T_H, O_V1T_L, F(O_HV), x_v, 32);
    add(O_G1T_H, O_G1T_L, F(O_HG), x_g, 128);
    gemm_split<<<dim3(cum), dim3(256), 0, stream>>>(G);
  }

  // G2 (fp32 oracle): LoRA-up with fused activations/epilogues.
  {
    Jobs G{};
    int cum = 0, i = 0;
    auto add = [&](const float* A, const float* W, float* C, const float* bias,
                   int K, int aact, int epi) {
      cum += 32 * 32;
      G.j[i++] = Job{A, W, C, bias, nullptr, nullptr, nullptr, 2048, K, 32, aact, epi, cum};
    };
    add(F(O_HW), w2, F(O_WDEC), w0, 64, 1, 2);
    add(F(O_HA), a2, F(O_AMAT), a0, 64, 0, 1);
    add(F(O_HV), v2, F(O_VMIX), v0, 32, 0, 1);
    add(F(O_HG), g2, outp,     nullptr, 128, 2, 0);
    gemm_oracle<<<dim3(cum), dim3(256), 0, stream>>>(G);
  }

  // prescan: kk-norm; k->k2, v->v', amat->a_in, vmix->b_in.
  prescan<<<dim3(65536), dim3(64), 0, stream>>>(F(O_K), F(O_V), F(O_AMAT), F(O_VMIX),
                                                vfirst, k_k, k_a);

  // scan v2: 64 blocks x 256 threads; o overwrites ain region (chunk c < c+1, safe).
  wkv_scan4<<<dim3(64), dim3(256), 0, stream>>>(F(O_R), F(O_K), F(O_WDEC), F(O_AIN),
                                                F(O_BIN), F(O_V), wkv0, F(O_O));

  // post: GroupNorm + bonus + gate -> afin.
  post<<<dim3(65536), dim3(64), 0, stream>>>(F(O_O), F(O_R), F(O_K), F(O_V),
                                             outp, r_k, ln_w, ln_b, F(O_AFIN));

  // T2: W_o transpose+split into dead r region, then G3 (split MFMA): out = afin @ W_o.
  {
    TJobs TO{};
    TO.j[0] = TJob{W_o, U(O_WOT_H), U(O_WOT_L), 2048, 32, 1024};
    wtrans<<<dim3(1024), dim3(256), 0, stream>>>(TO);
    GJobs G{};
    G.j[0] = GJob{F(O_AFIN), U(O_WOT_H), U(O_WOT_L), outp, nullptr, nullptr,
                  2048, 2048, 16, 256};
    gemm_split<<<dim3(256), dim3(256), 0, stream>>>(G);
  }

  (void)in_sizes; (void)n_in; (void)out_size; (void)ws_size;
}